// Round 4
// baseline (672.473 us; speedup 1.0000x reference)
//
#include <hip/hip_runtime.h>

// VectorQuantizer forward: inputs [64,2048,64] f32, codebook [1024,64] f32.
// Outputs concatenated in d_out (f32): quantized_ste [8388608], loss [1], indices-as-float [131072].
//
// Round 4: rounds 2-3 showed FETCH_SIZE ~28 GB (ideal ~0.2 GB): the compiler
// REMATERIALIZES the xr[64] global loads inside the k-loop instead of keeping
// the row register-resident (VGPR_Count 72 = c-prefetch only). Fix: pin each
// row element with an opaque empty asm ("+v") right after the load — remat of
// an asm-defined value is impossible, so the row must stay in VGPRs.
//
// Numerics contract (absmax 0.0 in rounds 1-3): fp32 chains
// d0:dims0-15, d1:16-31, d2:32-47, d3:48-63, combined (d0+d1)+(d2+d3);
// d2 = fl(fl(A - 2*dot) + csq[k]); scan k ascending, strict '<' (first min wins).

#define NROWS  131072
#define DIM    64
#define KCB    1024
#define KT     128            // codebook rows per LDS tile
#define NTILES (KCB / KT)     // 8
#define RPB    256            // rows per block = threads per block
#define QSIZE  (NROWS * DIM)  // 8388608

__global__ __launch_bounds__(256) void vq_prep(const float* __restrict__ cb,
                                               float* __restrict__ csq,
                                               float* __restrict__ loss_slot) {
    int k = blockIdx.x * 256 + threadIdx.x;
    if (k < KCB) {
        const float* c = cb + k * DIM;
        float a0 = 0.f, a1 = 0.f, a2 = 0.f, a3 = 0.f;
        #pragma unroll
        for (int d = 0; d < 16; ++d) {
            a0 = fmaf(c[d],      c[d],      a0);
            a1 = fmaf(c[16 + d], c[16 + d], a1);
            a2 = fmaf(c[32 + d], c[32 + d], a2);
            a3 = fmaf(c[48 + d], c[48 + d], a3);
        }
        csq[k] = (a0 + a1) + (a2 + a3);
    }
    if (blockIdx.x == 0 && threadIdx.x == 0) *loss_slot = 0.f;  // zero loss accumulator every call
}

__global__ __launch_bounds__(256, 2) void vq_main(const float* __restrict__ x,
                                                  const float* __restrict__ cb,
                                                  const float* __restrict__ csq,
                                                  float* __restrict__ out_q,
                                                  float* __restrict__ out_loss,
                                                  float* __restrict__ out_idx) {
    __shared__ float4 s_cb4[KT * DIM / 4];   // 32 KB: one codebook tile
    __shared__ float  s_csq[KCB];            // 4 KB: all code norms
    __shared__ int    s_final[RPB];
    __shared__ float  s_loss[4];

    const int tid  = threadIdx.x;
    const int lane = tid & 63;
    const int wid  = tid >> 6;
    const int row  = blockIdx.x * RPB + tid;

    // stage csq once (4 floats/thread, coalesced)
    #pragma unroll
    for (int j = 0; j < KCB / 256; ++j) s_csq[tid + 256 * j] = csq[tid + 256 * j];

    // ---- load this thread's row into registers and PIN it there ----
    float xr[DIM];
    const float4* xv = reinterpret_cast<const float4*>(x + (size_t)row * DIM);
    #pragma unroll
    for (int i = 0; i < DIM / 4; ++i) {
        float4 v = xv[i];
        xr[4 * i + 0] = v.x; xr[4 * i + 1] = v.y;
        xr[4 * i + 2] = v.z; xr[4 * i + 3] = v.w;
    }
    // Opaque register pin: the compiler cannot rematerialize (re-load) a value
    // that an asm statement defines. This is what keeps FETCH_SIZE at ~0.2 GB
    // instead of 28 GB (rounds 2-3 failure mode).
    #pragma unroll
    for (int d = 0; d < DIM; ++d) asm volatile("" : "+v"(xr[d]));

    // ---- A = sum(x^2), same chain order as the passing rounds ----
    float a0 = 0.f, a1 = 0.f, a2 = 0.f, a3 = 0.f;
    #pragma unroll
    for (int d = 0; d < 16; ++d) {
        a0 = fmaf(xr[d],      xr[d],      a0);
        a1 = fmaf(xr[16 + d], xr[16 + d], a1);
        a2 = fmaf(xr[32 + d], xr[32 + d], a2);
        a3 = fmaf(xr[48 + d], xr[48 + d], a3);
    }
    const float A = (a0 + a1) + (a2 + a3);

    // ---- scan all K in LDS tiles; k is block-uniform -> LDS broadcast ----
    float best = 3.4e38f;
    int   bidx = 0;
    for (int t = 0; t < NTILES; ++t) {
        __syncthreads();   // protect previous tile's readers
        // stage tile t: 2048 float4s, 8 per thread, coalesced
        const float4* gsrc = reinterpret_cast<const float4*>(cb) + t * (KT * DIM / 4);
        #pragma unroll
        for (int j = 0; j < KT * DIM / 4 / 256; ++j)
            s_cb4[tid + 256 * j] = gsrc[tid + 256 * j];
        __syncthreads();

        #pragma unroll 2
        for (int kk = 0; kk < KT; ++kk) {
            const float4* c4 = &s_cb4[kk * (DIM / 4)];
            float d0 = 0.f, d1 = 0.f, d2c = 0.f, d3 = 0.f;
            #pragma unroll
            for (int j = 0; j < 4; ++j) {
                float4 v0 = c4[j];          // dims 4j..4j+3     (0..15)
                float4 v1 = c4[4 + j];      // (16..31)
                float4 v2 = c4[8 + j];      // (32..47)
                float4 v3 = c4[12 + j];     // (48..63)
                d0  = fmaf(xr[4 * j + 0],      v0.x, d0);
                d0  = fmaf(xr[4 * j + 1],      v0.y, d0);
                d0  = fmaf(xr[4 * j + 2],      v0.z, d0);
                d0  = fmaf(xr[4 * j + 3],      v0.w, d0);
                d1  = fmaf(xr[16 + 4 * j + 0], v1.x, d1);
                d1  = fmaf(xr[16 + 4 * j + 1], v1.y, d1);
                d1  = fmaf(xr[16 + 4 * j + 2], v1.z, d1);
                d1  = fmaf(xr[16 + 4 * j + 3], v1.w, d1);
                d2c = fmaf(xr[32 + 4 * j + 0], v2.x, d2c);
                d2c = fmaf(xr[32 + 4 * j + 1], v2.y, d2c);
                d2c = fmaf(xr[32 + 4 * j + 2], v2.z, d2c);
                d2c = fmaf(xr[32 + 4 * j + 3], v2.w, d2c);
                d3  = fmaf(xr[48 + 4 * j + 0], v3.x, d3);
                d3  = fmaf(xr[48 + 4 * j + 1], v3.y, d3);
                d3  = fmaf(xr[48 + 4 * j + 2], v3.z, d3);
                d3  = fmaf(xr[48 + 4 * j + 3], v3.w, d3);
            }
            const float dot = (d0 + d1) + (d2c + d3);
            const int   k   = t * KT + kk;
            const float tt  = A - 2.0f * dot;    // 2*dot exact; one rounding
            const float dd  = tt + s_csq[k];     // second rounding, ref expr
            if (dd < best) { best = dd; bidx = k; }  // strict '<': first index wins
        }
    }

    s_final[tid] = bidx;
    out_idx[row] = (float)bidx;
    __syncthreads();

    // ---- epilogue: coalesced STE write + loss partial ----
    const size_t base = (size_t)blockIdx.x * RPB * DIM;
    float lsum = 0.f;
    #pragma unroll 4
    for (int i = tid; i < RPB * DIM; i += 256) {
        const int r = i >> 6;
        const int d = i & 63;
        const int kb = s_final[r];
        const float q  = cb[(size_t)kb * DIM + d];
        const float xe = x[base + i];
        out_q[base + i] = xe + (q - xe);     // STE forward, ref's rounding
        const float df = q - xe;
        lsum = fmaf(df, df, lsum);
    }
    #pragma unroll
    for (int off = 32; off; off >>= 1) lsum += __shfl_down(lsum, off, 64);
    if (lane == 0) s_loss[wid] = lsum;
    __syncthreads();
    if (tid == 0) {
        const float tot = (s_loss[0] + s_loss[1]) + (s_loss[2] + s_loss[3]);
        atomicAdd(out_loss, tot * (1.25f / 8388608.0f));  // (q + 0.25*e) / count
    }
}

extern "C" void kernel_launch(void* const* d_in, const int* in_sizes, int n_in,
                              void* d_out, int out_size, void* d_ws, size_t ws_size,
                              hipStream_t stream) {
    const float* x  = (const float*)d_in[0];   // 8388608
    const float* cb = (const float*)d_in[1];   // 65536
    float* out      = (float*)d_out;
    float* out_loss = out + QSIZE;             // [8388608]
    float* out_idx  = out + QSIZE + 1;         // [8388609 .. 8519680]
    float* csq      = (float*)d_ws;            // 1024 floats scratch

    vq_prep<<<4, 256, 0, stream>>>(cb, csq, out_loss);
    vq_main<<<NROWS / RPB, 256, 0, stream>>>(x, cb, csq, out, out_loss, out_idx);
}

// Round 5
// 503.139 us; speedup vs baseline: 1.3366x; 1.3366x over previous
//
#include <hip/hip_runtime.h>

// VectorQuantizer forward: inputs [64,2048,64] f32, codebook [1024,64] f32.
// Outputs concatenated in d_out (f32): quantized_ste [8388608], loss [1], indices-as-float [131072].
//
// Round 5: round-4 established the binding resource is the LDS return path:
// 512 thr/CU x 1024 k x 256 B lane-delivered = 134 MB/CU at ~85 B/cyc
// => 657 us predicted, 660 us observed. The code row is wave-uniform per k,
// so move the broadcast to SGPRs: s_load_dwordx16 x4 per k (256 B per WAVE,
// not per lane - 64x less broadcast traffic, on the scalar pipe) and
// v_fmac_f32 with SGPR multiplicand. No LDS in the main loop at all.
//
// Numerics contract (absmax 0.0 in rounds 1-4): fp32 chains
// d0:dims0-15, d1:16-31, d2:32-47, d3:48-63, combined (d0+d1)+(d2+d3);
// d2 = fl(fl(A - 2*dot) + csq[k]); scan k ascending, strict '<' (first min wins).

#define NROWS  131072
#define DIM    64
#define KCB    1024
#define RPB    256            // rows per block = threads per block
#define QSIZE  (NROWS * DIM)  // 8388608

typedef __attribute__((ext_vector_type(16))) float sfloat16;

__global__ __launch_bounds__(256) void vq_prep(const float* __restrict__ cb,
                                               float* __restrict__ csq,
                                               float* __restrict__ loss_slot) {
    int k = blockIdx.x * 256 + threadIdx.x;
    if (k < KCB) {
        const float* c = cb + k * DIM;
        float a0 = 0.f, a1 = 0.f, a2 = 0.f, a3 = 0.f;
        #pragma unroll
        for (int d = 0; d < 16; ++d) {
            a0 = fmaf(c[d],      c[d],      a0);
            a1 = fmaf(c[16 + d], c[16 + d], a1);
            a2 = fmaf(c[32 + d], c[32 + d], a2);
            a3 = fmaf(c[48 + d], c[48 + d], a3);
        }
        csq[k] = (a0 + a1) + (a2 + a3);
    }
    if (blockIdx.x == 0 && threadIdx.x == 0) *loss_slot = 0.f;  // zero loss accumulator every call
}

__global__ __launch_bounds__(256, 2) void vq_main(const float* __restrict__ x,
                                                  const float* __restrict__ cb,
                                                  const float* __restrict__ csq,
                                                  float* __restrict__ out_q,
                                                  float* __restrict__ out_loss,
                                                  float* __restrict__ out_idx) {
    __shared__ int   s_final[RPB];
    __shared__ float s_loss[4];

    const int tid  = threadIdx.x;
    const int lane = tid & 63;
    const int wid  = tid >> 6;
    const int row  = blockIdx.x * RPB + tid;

    // ---- load this thread's row into registers ----
    float xr[DIM];
    const float4* xv = reinterpret_cast<const float4*>(x + (size_t)row * DIM);
    #pragma unroll
    for (int i = 0; i < DIM / 4; ++i) {
        float4 v = xv[i];
        xr[4 * i + 0] = v.x; xr[4 * i + 1] = v.y;
        xr[4 * i + 2] = v.z; xr[4 * i + 3] = v.w;
    }

    // ---- A = sum(x^2), same chain order as the passing rounds ----
    {
    }
    float a0 = 0.f, a1 = 0.f, a2 = 0.f, a3 = 0.f;
    #pragma unroll
    for (int d = 0; d < 16; ++d) {
        a0 = fmaf(xr[d],      xr[d],      a0);
        a1 = fmaf(xr[16 + d], xr[16 + d], a1);
        a2 = fmaf(xr[32 + d], xr[32 + d], a2);
        a3 = fmaf(xr[48 + d], xr[48 + d], a3);
    }
    const float A = (a0 + a1) + (a2 + a3);

    // ---- scan all K; code row broadcast via SGPRs (scalar pipe, no LDS) ----
    float best = 3.4e38f;
    int   bidx = 0;
    #pragma clang loop unroll(disable)
    for (int k = 0; k < KCB; ++k) {
        const float* cbk = cb + ((size_t)k << 6);   // uniform -> SGPR pair
        sfloat16 c0, c1, c2, c3;
        float sqk;
        asm volatile("s_load_dwordx16 %0, %1, 0x0"  : "=s"(c0) : "s"(cbk));
        asm volatile("s_load_dwordx16 %0, %1, 0x40" : "=s"(c1) : "s"(cbk));
        asm volatile("s_load_dwordx16 %0, %1, 0x80" : "=s"(c2) : "s"(cbk));
        asm volatile("s_load_dwordx16 %0, %1, 0xc0" : "=s"(c3) : "s"(cbk));
        asm volatile("s_load_dword %0, %1, 0x0"     : "=s"(sqk) : "s"(csq + k));
        // The wait carries the loaded regs as operands so no use can be
        // scheduled above it.
        asm volatile("s_waitcnt lgkmcnt(0)"
                     : "+s"(c0), "+s"(c1), "+s"(c2), "+s"(c3), "+s"(sqk));

        float d0 = 0.f, d1 = 0.f, d2c = 0.f, d3 = 0.f;
        #pragma unroll
        for (int d = 0; d < 16; ++d) {
            d0  = fmaf(xr[d],      c0[d], d0);
            d1  = fmaf(xr[16 + d], c1[d], d1);
            d2c = fmaf(xr[32 + d], c2[d], d2c);
            d3  = fmaf(xr[48 + d], c3[d], d3);
        }
        const float dot = (d0 + d1) + (d2c + d3);
        const float tt  = A - 2.0f * dot;    // 2*dot exact; one rounding
        const float dd  = tt + sqk;          // second rounding, ref expr
        if (dd < best) { best = dd; bidx = k; }  // strict '<': first index wins
    }

    s_final[tid] = bidx;
    out_idx[row] = (float)bidx;
    __syncthreads();

    // ---- epilogue: coalesced STE write + loss partial ----
    const size_t base = (size_t)blockIdx.x * RPB * DIM;
    float lsum = 0.f;
    #pragma unroll 4
    for (int i = tid; i < RPB * DIM; i += 256) {
        const int r = i >> 6;
        const int d = i & 63;
        const int kb = s_final[r];
        const float q  = cb[(size_t)kb * DIM + d];
        const float xe = x[base + i];
        out_q[base + i] = xe + (q - xe);     // STE forward, ref's rounding
        const float df = q - xe;
        lsum = fmaf(df, df, lsum);
    }
    #pragma unroll
    for (int off = 32; off; off >>= 1) lsum += __shfl_down(lsum, off, 64);
    if (lane == 0) s_loss[wid] = lsum;
    __syncthreads();
    if (tid == 0) {
        const float tot = (s_loss[0] + s_loss[1]) + (s_loss[2] + s_loss[3]);
        atomicAdd(out_loss, tot * (1.25f / 8388608.0f));  // (q + 0.25*e) / count
    }
}

extern "C" void kernel_launch(void* const* d_in, const int* in_sizes, int n_in,
                              void* d_out, int out_size, void* d_ws, size_t ws_size,
                              hipStream_t stream) {
    const float* x  = (const float*)d_in[0];   // 8388608
    const float* cb = (const float*)d_in[1];   // 65536
    float* out      = (float*)d_out;
    float* out_loss = out + QSIZE;             // [8388608]
    float* out_idx  = out + QSIZE + 1;         // [8388609 .. 8519680]
    float* csq      = (float*)d_ws;            // 1024 floats scratch

    vq_prep<<<4, 256, 0, stream>>>(cb, csq, out_loss);
    vq_main<<<NROWS / RPB, 256, 0, stream>>>(x, cb, csq, out, out_loss, out_idx);
}

// Round 6
// 339.460 us; speedup vs baseline: 1.9810x; 1.4822x over previous
//
#include <hip/hip_runtime.h>

// VectorQuantizer forward: inputs [64,2048,64] f32, codebook [1024,64] f32.
// Outputs concatenated in d_out (f32): quantized_ste [8388608], loss [1], indices-as-float [131072].
//
// Round 6: round-5 (SGPR broadcast) became SMEM-latency-serialized: per k,
// s_load(~380 cyc L2) + lgkmcnt(0) + 145 VALU cyc => 525 cyc/k x 1024 k per
// wave = 224 us serial chain (obs 447 with 2 waves/SIMD). SGPR double-buffer
// is impossible (64-reg row; SMEM returns out-of-order => only lgkmcnt(0) is
// safe). Fix: K-SPLIT across the block's 4 waves (64 rows/block, one lane per
// row; wave w scans k in [256w, 256w+256)). Serial chain /4; total VALU issue
// unchanged => VALU-issue-bound ~126 us. Uniformity of the wave's k-base is
// forced with readfirstlane so the s_load stays scalar (round-1's failure).
//
// Numerics contract (absmax 0.0 in rounds 1-5): fp32 chains
// d0:dims0-15, d1:16-31, d2:32-47, d3:48-63, combined (d0+d1)+(d2+d3);
// d2 = fl(fl(A - 2*dot) + csq[k]); per-wave scan k ascending with strict '<';
// cross-wave combine in ascending-K order with strict '<' (first min wins).

#define NROWS  131072
#define DIM    64
#define KCB    1024
#define KW     256            // k's per wave
#define RPB    64             // rows per block (one lane per row)
#define QSIZE  (NROWS * DIM)  // 8388608

typedef __attribute__((ext_vector_type(16))) float sfloat16;

__global__ __launch_bounds__(256) void vq_prep(const float* __restrict__ cb,
                                               float* __restrict__ csq,
                                               float* __restrict__ loss_slot) {
    int k = blockIdx.x * 256 + threadIdx.x;
    if (k < KCB) {
        const float* c = cb + k * DIM;
        float a0 = 0.f, a1 = 0.f, a2 = 0.f, a3 = 0.f;
        #pragma unroll
        for (int d = 0; d < 16; ++d) {
            a0 = fmaf(c[d],      c[d],      a0);
            a1 = fmaf(c[16 + d], c[16 + d], a1);
            a2 = fmaf(c[32 + d], c[32 + d], a2);
            a3 = fmaf(c[48 + d], c[48 + d], a3);
        }
        csq[k] = (a0 + a1) + (a2 + a3);
    }
    if (blockIdx.x == 0 && threadIdx.x == 0) *loss_slot = 0.f;  // zero loss accumulator every call
}

__global__ __launch_bounds__(256, 4) void vq_main(const float* __restrict__ x,
                                                  const float* __restrict__ cb,
                                                  const float* __restrict__ csq,
                                                  float* __restrict__ out_q,
                                                  float* __restrict__ out_loss,
                                                  float* __restrict__ out_idx) {
    __shared__ float s_best[4][RPB];
    __shared__ int   s_bidx[4][RPB];
    __shared__ int   s_final[RPB];
    __shared__ float s_loss[4];

    const int tid  = threadIdx.x;
    const int lane = tid & 63;
    const int wid  = tid >> 6;
    const int row  = blockIdx.x * RPB + lane;   // all 4 waves: same 64 rows

    // wave-uniform k-base, forced into an SGPR (round-1 lesson: threadIdx-
    // derived values are divergent-by-analysis and break scalar loads)
    const int kbase = __builtin_amdgcn_readfirstlane(wid << 8);

    // ---- load this thread's row into registers ----
    float xr[DIM];
    const float4* xv = reinterpret_cast<const float4*>(x + (size_t)row * DIM);
    #pragma unroll
    for (int i = 0; i < DIM / 4; ++i) {
        float4 v = xv[i];
        xr[4 * i + 0] = v.x; xr[4 * i + 1] = v.y;
        xr[4 * i + 2] = v.z; xr[4 * i + 3] = v.w;
    }

    // ---- A = sum(x^2), same chain order as the passing rounds ----
    float a0 = 0.f, a1 = 0.f, a2 = 0.f, a3 = 0.f;
    #pragma unroll
    for (int d = 0; d < 16; ++d) {
        a0 = fmaf(xr[d],      xr[d],      a0);
        a1 = fmaf(xr[16 + d], xr[16 + d], a1);
        a2 = fmaf(xr[32 + d], xr[32 + d], a2);
        a3 = fmaf(xr[48 + d], xr[48 + d], a3);
    }
    const float A = (a0 + a1) + (a2 + a3);

    // ---- scan this wave's K quarter; code row broadcast via SGPRs ----
    float best = 3.4e38f;
    int   bidx = kbase;
    #pragma clang loop unroll(disable)
    for (int kk = 0; kk < KW; ++kk) {
        const int k = kbase + kk;
        const float* cbk = cb + ((size_t)k << 6);
        sfloat16 c0, c1, c2, c3;
        float sqk;
        asm volatile("s_load_dwordx16 %0, %1, 0x0"  : "=s"(c0) : "s"(cbk));
        asm volatile("s_load_dwordx16 %0, %1, 0x40" : "=s"(c1) : "s"(cbk));
        asm volatile("s_load_dwordx16 %0, %1, 0x80" : "=s"(c2) : "s"(cbk));
        asm volatile("s_load_dwordx16 %0, %1, 0xc0" : "=s"(c3) : "s"(cbk));
        asm volatile("s_load_dword %0, %1, 0x0"     : "=s"(sqk) : "s"(csq + k));
        // carry the loaded regs so no use is scheduled above the wait
        asm volatile("s_waitcnt lgkmcnt(0)"
                     : "+s"(c0), "+s"(c1), "+s"(c2), "+s"(c3), "+s"(sqk));

        float d0 = 0.f, d1 = 0.f, d2c = 0.f, d3 = 0.f;
        #pragma unroll
        for (int d = 0; d < 16; ++d) {
            d0  = fmaf(xr[d],      c0[d], d0);
            d1  = fmaf(xr[16 + d], c1[d], d1);
            d2c = fmaf(xr[32 + d], c2[d], d2c);
            d3  = fmaf(xr[48 + d], c3[d], d3);
        }
        const float dot = (d0 + d1) + (d2c + d3);
        const float tt  = A - 2.0f * dot;    // 2*dot exact; one rounding
        const float dd  = tt + sqk;          // second rounding, ref expr
        if (dd < best) { best = dd; bidx = k; }  // strict '<': first index wins
    }

    s_best[wid][lane] = best;
    s_bidx[wid][lane] = bidx;
    __syncthreads();

    // ---- cross-wave combine, ascending-K order, strict '<' (first min wins) ----
    if (tid < RPB) {
        float b = s_best[0][tid];
        int   i = s_bidx[0][tid];
        #pragma unroll
        for (int w = 1; w < 4; ++w) {
            const float bw = s_best[w][tid];
            const int   iw = s_bidx[w][tid];
            if (bw < b) { b = bw; i = iw; }
        }
        s_final[tid] = i;
        out_idx[blockIdx.x * RPB + tid] = (float)i;
    }
    __syncthreads();

    // ---- epilogue: coalesced STE write + loss partial ----
    const size_t base = (size_t)blockIdx.x * RPB * DIM;
    float lsum = 0.f;
    #pragma unroll 4
    for (int i = tid; i < RPB * DIM; i += 256) {
        const int r = i >> 6;
        const int d = i & 63;
        const int kb = s_final[r];
        const float q  = cb[(size_t)kb * DIM + d];
        const float xe = x[base + i];
        out_q[base + i] = xe + (q - xe);     // STE forward, ref's rounding
        const float df = q - xe;
        lsum = fmaf(df, df, lsum);
    }
    #pragma unroll
    for (int off = 32; off; off >>= 1) lsum += __shfl_down(lsum, off, 64);
    if (lane == 0) s_loss[wid] = lsum;
    __syncthreads();
    if (tid == 0) {
        const float tot = (s_loss[0] + s_loss[1]) + (s_loss[2] + s_loss[3]);
        atomicAdd(out_loss, tot * (1.25f / 8388608.0f));  // (q + 0.25*e) / count
    }
}

extern "C" void kernel_launch(void* const* d_in, const int* in_sizes, int n_in,
                              void* d_out, int out_size, void* d_ws, size_t ws_size,
                              hipStream_t stream) {
    const float* x  = (const float*)d_in[0];   // 8388608
    const float* cb = (const float*)d_in[1];   // 65536
    float* out      = (float*)d_out;
    float* out_loss = out + QSIZE;             // [8388608]
    float* out_idx  = out + QSIZE + 1;         // [8388609 .. 8519680]
    float* csq      = (float*)d_ws;            // 1024 floats scratch

    vq_prep<<<4, 256, 0, stream>>>(cb, csq, out_loss);
    vq_main<<<NROWS / RPB, 256, 0, stream>>>(x, cb, csq, out, out_loss, out_idx);
}